// Round 13
// baseline (442.244 us; speedup 1.0000x reference)
//
#include <hip/hip_runtime.h>
#include <cstdint>

#define SEG_CAP 20   // slots per (dst,class) key; Poisson(2.67) max over 300k keys ~14

typedef __attribute__((ext_vector_type(8))) short short8;
typedef __attribute__((ext_vector_type(4))) float f32x4;

static __device__ __forceinline__ unsigned short f2bf(float f) {
  unsigned int u = __float_as_uint(f);
  unsigned int r = (u + 0x7FFFu + ((u >> 16) & 1u)) >> 16;   // RNE
  return (unsigned short)r;
}
static __device__ __forceinline__ unsigned int pack2bf(float a, float b) {
  return (unsigned int)f2bf(a) | ((unsigned int)f2bf(b) << 16);
}
static __device__ __forceinline__ float2 bf2f(unsigned int u) {
  return make_float2(__uint_as_float(u << 16), __uint_as_float(u & 0xFFFF0000u));
}
static __device__ __forceinline__ void acc8(float* a, uint4 h, uint4 r) {
  float2 f, g;
  f = bf2f(h.x); g = bf2f(r.x); a[0] += f.x - g.x; a[1] += f.y - g.y;
  f = bf2f(h.y); g = bf2f(r.y); a[2] += f.x - g.x; a[3] += f.y - g.y;
  f = bf2f(h.z); g = bf2f(r.z); a[4] += f.x - g.x; a[5] += f.y - g.y;
  f = bf2f(h.w); g = bf2f(r.w); a[6] += f.x - g.x; a[7] += f.y - g.y;
}

// ---- one-shot prep kernel: r-chain, weight cvt, entity cvt, cursor zero,
// stat zero, key/pay precompute (R12-verified structure) ----
__global__ __launch_bounds__(256) void k_prep(
    const float* __restrict__ coeff, const float* __restrict__ bases,
    const float* __restrict__ selfr, const float* __restrict__ relw1,
    const float* __restrict__ relw2,
    unsigned int* __restrict__ rfb, unsigned int* __restrict__ r1b,
    float* __restrict__ r2,
    const float* __restrict__ W1, const float* __restrict__ W2,
    unsigned short* __restrict__ WT1, unsigned short* __restrict__ WT2,
    const float* __restrict__ ent, const int* __restrict__ ent_ids,
    unsigned int* __restrict__ entbf,
    int* __restrict__ cursor, float* __restrict__ stats,
    const int* __restrict__ ei, const int* __restrict__ et,
    const int* __restrict__ yk, int* __restrict__ keyA,
    unsigned int* __restrict__ payA, int nE,
    int nPairs, int nKeys, int cvtB, int cntB, int zeroB) {
  int b = blockIdx.x, tid = threadIdx.x;
  if (b < 201) {
    __shared__ float row[2][128], r1row[2][128];
    int half = tid >> 7, c = tid & 127;
    int r = 2 * b + half;
    bool ok = (r <= 400);
    if (ok) {
      float v;
      if (r == 400) {
        v = selfr[c];
      } else {
        int rr = (r < 200) ? r : r - 200;
        float s = 0.f;
#pragma unroll 10
        for (int k = 0; k < 50; ++k) s += coeff[rr * 50 + k] * bases[k * 128 + c];
        v = (r < 200) ? s : -s;
      }
      row[half][c] = v;
    }
    __syncthreads();
    if (ok && c < 64) rfb[r * 64 + c] = pack2bf(row[half][2 * c], row[half][2 * c + 1]);
    if (ok) {
      float s = 0.f;
#pragma unroll 8
      for (int k = 0; k < 128; ++k) s += row[half][k] * relw1[k * 128 + c];
      r1row[half][c] = s;
    }
    __syncthreads();
    if (ok && c < 64) r1b[r * 64 + c] = pack2bf(r1row[half][2 * c], r1row[half][2 * c + 1]);
    if (ok) {
      float s = 0.f;
#pragma unroll 8
      for (int k = 0; k < 128; ++k) s += r1row[half][k] * relw2[k * 128 + c];
      r2[r * 128 + c] = s;
    }
  } else if (b < 585) {
    int idx = (b - 201) * 256 + tid;
    const int half = 128 * 384;
    const float* W = (idx < half) ? W1 : W2;
    unsigned short* WT = (idx < half) ? WT1 : WT2;
    int id2 = (idx < half) ? idx : idx - half;
    int n = id2 & 127, k = id2 >> 7;
    int kk = k >> 7, kr = k & 127;
    WT[(size_t)n * 384 + k] = f2bf(W[(size_t)kk * 16384 + kr * 128 + n]);
  } else if (b < 585 + cvtB) {
    int i = (b - 585) * 256 + tid;
    if (i < nPairs) {
      int e = i >> 6;
      int src = ent_ids[e];
      float2 v = *(const float2*)&ent[(size_t)src * 128 + (i & 63) * 2];
      entbf[i] = pack2bf(v.x, v.y);
    }
  } else if (b < 585 + cvtB + cntB) {
    int i = (b - (585 + cvtB)) * 256 + tid;
    if (i < nKeys) cursor[i] = 0;
  } else if (b < 585 + cvtB + cntB + zeroB) {
    int i = (b - (585 + cvtB + cntB)) * 256 + tid;
    if (i < 16896) stats[i] = 0.f;
  } else {
    // key/pay precompute: one pass over edges
    int e = (b - (585 + cvtB + cntB + zeroB)) * 1024 + tid;
#pragma unroll
    for (int i = 0; i < 4; ++i, e += 256) {
      if (e < nE) {
        keyA[e] = ei[nE + e] * 3 + yk[e];
        payA[e] = (unsigned int)ei[e] | ((unsigned int)et[e] << 20);
      }
    }
  }
}

// ---- R13: the ONLY CSR kernel.  Fixed-capacity buckets: the atomic cursor
// IS the histogram; segment base is implicit (key*SEG_CAP).  Replaces
// hist + scan1 + scan2 + scan3 + fill (5 dispatches -> 1).  Range-partitioned
// (R9/R11-verified: keeps cursor atomics XCD-local).
__global__ __launch_bounds__(256) void k_fillR(const int* __restrict__ keyA,
                                               const unsigned int* __restrict__ payA,
                                               int* __restrict__ cursor,
                                               unsigned int* __restrict__ bucket, int nE, int rsz) {
  int r = blockIdx.x;
  int e0 = blockIdx.y * 1024;
#pragma unroll
  for (int i = 0; i < 4; ++i) {
    int e = e0 + i * 256 + threadIdx.x;
    if (e < nE) {
      int key = keyA[e];
      if (key / rsz == r) {
        int slot = atomicAdd(&cursor[key], 1);
        if (slot < SEG_CAP) bucket[(size_t)key * SEG_CAP + slot] = payA[e];
      }
    }
  }
}

// ---- FUSED gather-aggregate + GEMM + BN-stats, BM=32.
// R9 contiguous-walk pipeline retained via VIRTUAL index: j in [0,T6) with
// prefix-sum boundaries T1..T6 (same nextB chain); physical address
// addr(v) = v + D_s resolved by a 5-way branchless select (D_s = segment
// base - T_s).  Lengths come straight from the fill cursor (min w/ CAP).
__global__ __launch_bounds__(256, 6) void k_fused(
    const unsigned int* __restrict__ xb, const unsigned int* __restrict__ rb,
    const int* __restrict__ cursor, const unsigned int* __restrict__ packed,
    const unsigned short* __restrict__ WT, unsigned short* __restrict__ C,
    float* __restrict__ statsRep, int M) {
  __shared__ unsigned short As[32][392];
  const int tid = threadIdx.x;
  const int m0 = blockIdx.x * 32;
  const int wave = tid >> 6, lane = tid & 63;
  const int quad = lane >> 4, l16 = lane & 15;
  const int qid = (wave << 2) | quad;          // 0..15: rows 2qid, 2qid+1

  // ---- gather phase: virtual-index pipelined walk over 6 segments ----
  {
    const int dst0 = m0 + 2 * qid;
    const int base = dst0 * 3;
    int l0 = 0, l1 = 0, l2 = 0, l3 = 0, l4 = 0, l5 = 0;
    if (dst0 + 1 < M) {
      l0 = min(cursor[base],     SEG_CAP); l1 = min(cursor[base + 1], SEG_CAP);
      l2 = min(cursor[base + 2], SEG_CAP); l3 = min(cursor[base + 3], SEG_CAP);
      l4 = min(cursor[base + 4], SEG_CAP); l5 = min(cursor[base + 5], SEG_CAP);
    } else if (dst0 < M) {
      l0 = min(cursor[base],     SEG_CAP); l1 = min(cursor[base + 1], SEG_CAP);
      l2 = min(cursor[base + 2], SEG_CAP);
    }
    const int T1 = l0, T2 = T1 + l1, T3 = T2 + l2;
    const int T4 = T3 + l3, T5 = T4 + l4, T6 = T5 + l5;
    const int A0 = base * SEG_CAP;
    const int D0 = A0;
    const int D1 = A0 + SEG_CAP     - T1;
    const int D2 = A0 + 2 * SEG_CAP - T2;
    const int D3 = A0 + 3 * SEG_CAP - T3;
    const int D4 = A0 + 4 * SEG_CAP - T4;
    const int D5 = A0 + 5 * SEG_CAP - T5;

    auto vaddr = [&](int v) {
      int d = D0;
      d = (v >= T1) ? D1 : d;
      d = (v >= T2) ? D2 : d;
      d = (v >= T3) ? D3 : d;
      d = (v >= T4) ? D4 : d;
      d = (v >= T5) ? D5 : d;
      return v + d;
    };

    float ac[8] = {};
    int seg = 0;
    int nextB = T1;
    int j = 0;
    const int hi = T6;
    unsigned short* lds0 = &As[2 * qid][0];

    auto flushSeg = [&]() {
      int rowOff = (seg >= 3) ? 392 : 0;
      int cls = seg - ((seg >= 3) ? 3 : 0);
      uint4 ov;
      ov.x = pack2bf(ac[0], ac[1]);
      ov.y = pack2bf(ac[2], ac[3]);
      ov.z = pack2bf(ac[4], ac[5]);
      ov.w = pack2bf(ac[6], ac[7]);
      *(uint4*)(lds0 + rowOff + cls * 128 + l16 * 8) = ov;
#pragma unroll
      for (int z = 0; z < 8; ++z) ac[z] = 0.f;
      ++seg;
      nextB = (seg == 1) ? T2 : (seg == 2) ? T3 : (seg == 3) ? T4
            : (seg == 4) ? T5 : T6;
    };

    if (j < hi) {
      int jc1 = (1 < hi) ? 1 : 0;
      unsigned int q0 = packed[vaddr(0)], q1 = packed[vaddr(jc1)];
      int s0 = q0 & 0xFFFFF, t0 = q0 >> 20;
      int s1 = q1 & 0xFFFFF, t1 = q1 >> 20;
      uint4 h0 = *(const uint4*)&xb[(size_t)s0 * 64 + l16 * 4];
      uint4 r0 = *(const uint4*)&rb[(size_t)t0 * 64 + l16 * 4];
      uint4 h1 = *(const uint4*)&xb[(size_t)s1 * 64 + l16 * 4];
      uint4 r1 = *(const uint4*)&rb[(size_t)t1 * 64 + l16 * 4];
      while (j < hi) {
        int jp2 = (j + 2 < hi) ? j + 2 : hi - 1;
        int jp3 = (j + 3 < hi) ? j + 3 : hi - 1;
        unsigned int q2 = packed[vaddr(jp2)], q3 = packed[vaddr(jp3)];
        int s2 = q2 & 0xFFFFF, t2 = q2 >> 20;
        int s3 = q3 & 0xFFFFF, t3 = q3 >> 20;
        uint4 th0 = *(const uint4*)&xb[(size_t)s2 * 64 + l16 * 4];
        uint4 tr0 = *(const uint4*)&rb[(size_t)t2 * 64 + l16 * 4];
        uint4 th1 = *(const uint4*)&xb[(size_t)s3 * 64 + l16 * 4];
        uint4 tr1 = *(const uint4*)&rb[(size_t)t3 * 64 + l16 * 4];
        while (j == nextB) flushSeg();
        acc8(ac, h0, r0);
        ++j;
        if (j < hi) {
          while (j == nextB) flushSeg();
          acc8(ac, h1, r1);
          ++j;
        }
        h0 = th0; r0 = tr0; h1 = th1; r1 = tr1;
      }
    }
    while (seg < 6) flushSeg();
  }
  __syncthreads();

  // ---- GEMM phase: C[32x128] = As[32x384] @ WT^T, B streamed from L2 ----
  const unsigned short* Wp = WT + (size_t)(wave * 32 + l16) * 384 + quad * 8;
  short8 bc0 = *(const short8*)(Wp);
  short8 bc1 = *(const short8*)(Wp + 16 * 384);
  f32x4 acc[2][2] = {};
#pragma unroll 1
  for (int it = 0; it < 12; ++it) {
    short8 bn0, bn1;
    if (it < 11) {
      bn0 = *(const short8*)(Wp + (it + 1) * 32);
      bn1 = *(const short8*)(Wp + 16 * 384 + (it + 1) * 32);
    }
    short8 a0 = *(const short8*)&As[l16][it * 32 + quad * 8];
    short8 a1 = *(const short8*)&As[16 + l16][it * 32 + quad * 8];
    acc[0][0] = __builtin_amdgcn_mfma_f32_16x16x32_bf16(a0, bc0, acc[0][0], 0, 0, 0);
    acc[0][1] = __builtin_amdgcn_mfma_f32_16x16x32_bf16(a0, bc1, acc[0][1], 0, 0, 0);
    acc[1][0] = __builtin_amdgcn_mfma_f32_16x16x32_bf16(a1, bc0, acc[1][0], 0, 0, 0);
    acc[1][1] = __builtin_amdgcn_mfma_f32_16x16x32_bf16(a1, bc1, acc[1][1], 0, 0, 0);
    if (it < 11) { bc0 = bn0; bc1 = bn1; }
  }

  // ---- epilogue: bf16 C store + BN stats (in-register quad reduce) ----
  float ps[2] = {}, pq[2] = {};
#pragma unroll
  for (int t = 0; t < 2; ++t)
#pragma unroll
    for (int reg = 0; reg < 4; ++reg) {
      int m = m0 + t * 16 + quad * 4 + reg;
      if (m < M) {
#pragma unroll
        for (int ct = 0; ct < 2; ++ct) {
          float v = acc[t][ct][reg];
          int col = wave * 32 + ct * 16 + l16;
          C[(size_t)m * 128 + col] = f2bf(v);
          ps[ct] += v; pq[ct] += v * v;
        }
      }
    }
#pragma unroll
  for (int ct = 0; ct < 2; ++ct) {
    ps[ct] += __shfl_xor(ps[ct], 16);
    ps[ct] += __shfl_xor(ps[ct], 32);
    pq[ct] += __shfl_xor(pq[ct], 16);
    pq[ct] += __shfl_xor(pq[ct], 32);
  }
  if (quad == 0) {
    float* rep = statsRep + ((blockIdx.x & 31) << 8);
#pragma unroll
    for (int ct = 0; ct < 2; ++ct) {
      int col = wave * 32 + ct * 16 + l16;
      atomicAdd(&rep[col], ps[ct]);
      atomicAdd(&rep[128 + col], pq[ct]);
    }
  }
}

// norm + tanh (layer 1 only), uint4-vectorized; inline replica collapse
__global__ void k_norm(const uint4* __restrict__ Cb4, const float* __restrict__ rep,
                       const float* __restrict__ gamma, const float* __restrict__ beta,
                       float invN, uint4* __restrict__ xb4, int nQuad) {
  __shared__ float sc_s[128], bi_s[128];
  if (threadIdx.x < 128) {
    int c = threadIdx.x;
    float s = 0.f, q = 0.f;
#pragma unroll
    for (int r = 0; r < 32; ++r) {
      s += rep[r * 256 + c];
      q += rep[r * 256 + 128 + c];
    }
    float mean = s * invN;
    float var = fmaxf(q * invN - mean * mean, 0.f);
    float sc = rsqrtf(var + 1e-5f) * gamma[c];
    sc_s[c] = sc;
    bi_s[c] = beta[c] - mean * sc;
  }
  __syncthreads();
  int i = blockIdx.x * blockDim.x + threadIdx.x;
  if (i >= nQuad) return;
  uint4 v = Cb4[i];
  int j = (i * 4) & 63;
  uint4 o;
  float2 f;
  f = bf2f(v.x);
  o.x = pack2bf(tanhf(fmaf(f.x, sc_s[2*j],   bi_s[2*j])),   tanhf(fmaf(f.y, sc_s[2*j+1], bi_s[2*j+1])));
  f = bf2f(v.y);
  o.y = pack2bf(tanhf(fmaf(f.x, sc_s[2*j+2], bi_s[2*j+2])), tanhf(fmaf(f.y, sc_s[2*j+3], bi_s[2*j+3])));
  f = bf2f(v.z);
  o.z = pack2bf(tanhf(fmaf(f.x, sc_s[2*j+4], bi_s[2*j+4])), tanhf(fmaf(f.y, sc_s[2*j+5], bi_s[2*j+5])));
  f = bf2f(v.w);
  o.w = pack2bf(tanhf(fmaf(f.x, sc_s[2*j+6], bi_s[2*j+6])), tanhf(fmaf(f.y, sc_s[2*j+7], bi_s[2*j+7])));
  xb4[i] = o;
}

// scoring with layer-2 norm fused (R12-verified)
__global__ void k_score(const unsigned int* __restrict__ Cbu, const float* __restrict__ rep,
                        const float* __restrict__ gamma, const float* __restrict__ beta,
                        float invN, const float* __restrict__ r,
                        const int* __restrict__ triples, float* __restrict__ out, int nT) {
  __shared__ float sc_s[128], bi_s[128];
  if (threadIdx.x < 128) {
    int c = threadIdx.x;
    float s = 0.f, q = 0.f;
#pragma unroll
    for (int rr = 0; rr < 32; ++rr) {
      s += rep[rr * 256 + c];
      q += rep[rr * 256 + 128 + c];
    }
    float mean = s * invN;
    float var = fmaxf(q * invN - mean * mean, 0.f);
    float sc = rsqrtf(var + 1e-5f) * gamma[c];
    sc_s[c] = sc;
    bi_s[c] = beta[c] - mean * sc;
  }
  __syncthreads();
  int gid = blockIdx.x * blockDim.x + threadIdx.x;
  int t = gid >> 6;
  if (t >= nT) return;
  int lane = gid & 63;
  int h = triples[t * 3], rel = triples[t * 3 + 1], tl = triples[t * 3 + 2];
  float2 a = bf2f(Cbu[(size_t)h * 64 + lane]);
  float2 b = *(const float2*)&r[(size_t)rel * 128 + lane * 2];
  float2 cc = bf2f(Cbu[(size_t)tl * 64 + lane]);
  float ax = tanhf(fmaf(a.x, sc_s[2 * lane], bi_s[2 * lane]));
  float ay = tanhf(fmaf(a.y, sc_s[2 * lane + 1], bi_s[2 * lane + 1]));
  float cx = tanhf(fmaf(cc.x, sc_s[2 * lane], bi_s[2 * lane]));
  float cy = tanhf(fmaf(cc.y, sc_s[2 * lane + 1], bi_s[2 * lane + 1]));
  float s = fabsf(ax + b.x - cx) + fabsf(ay + b.y - cy);
#pragma unroll
  for (int off = 32; off > 0; off >>= 1) s += __shfl_down(s, off);
  if (lane == 0) out[t] = s;
}

extern "C" void kernel_launch(void* const* d_in, const int* in_sizes, int n_in,
                              void* d_out, int out_size, void* d_ws, size_t ws_size,
                              hipStream_t stream) {
  const float* ent   = (const float*)d_in[0];
  const float* bases = (const float*)d_in[1];
  const float* coeff = (const float*)d_in[2];
  const float* selfr = (const float*)d_in[3];
  const float* W1    = (const float*)d_in[4];
  const float* relw1 = (const float*)d_in[5];
  const float* g1    = (const float*)d_in[6];
  const float* b1    = (const float*)d_in[7];
  const float* W2    = (const float*)d_in[8];
  const float* relw2 = (const float*)d_in[9];
  const float* g2    = (const float*)d_in[10];
  const float* b2    = (const float*)d_in[11];
  const int* ent_ids = (const int*)d_in[12];
  const int* ei      = (const int*)d_in[13];
  const int* et      = (const int*)d_in[14];
  const int* yk      = (const int*)d_in[15];
  const int* triples = (const int*)d_in[16];

  const int M  = in_sizes[0] / 128;   // 100000
  const int nE = in_sizes[14];        // 800000
  const int nT = in_sizes[16] / 3;    // 4096
  const int nKeys = M * 3;
  const int rsz = (nKeys + 7) / 8;

  // workspace layout (~109 MB)
  float* p = (float*)d_ws;
  float* r2    = p; p += 401 * 128;
  float* statsAll = p; p += 16896;     // rep1(32x256) | rep2(32x256) | spare
  float* rep1 = statsAll;
  float* rep2 = statsAll + 32 * 256;
  unsigned short* Cb  = (unsigned short*)p;                       // M*128 bf16
  unsigned int* entbf = (unsigned int*)(Cb + (size_t)M * 128);    // M*64
  unsigned int* xb    = entbf + (size_t)M * 64;                   // M*64
  unsigned int* rfb   = xb + (size_t)M * 64;                      // 401*64
  unsigned int* r1b   = rfb + 401 * 64;                           // 401*64
  unsigned short* WT1 = (unsigned short*)(r1b + 401 * 64);
  unsigned short* WT2 = WT1 + 128 * 384;
  int* cursor  = (int*)(WT2 + 128 * 384);                         // nKeys
  unsigned int* bucket = (unsigned int*)(cursor + nKeys);         // nKeys*SEG_CAP
  int* keyA = (int*)(bucket + (size_t)nKeys * SEG_CAP);           // nE
  unsigned int* payA = (unsigned int*)(keyA + nE);                // nE

  float* out = (float*)d_out;

  const int nPairs = M * 64;
  const int nQuad  = M * 16;
  const int cvtB = (nPairs + 255) / 256;
  const int cntB = (nKeys + 255) / 256;
  const int zeroB = 66;
  const int kpB = (nE + 1023) / 1024;
  const int prepBlocks = 585 + cvtB + cntB + zeroB + kpB;
  const int fusedBlocks = (M + 31) / 32;
  const int normBlocks = (nQuad + 255) / 256;
  const dim3 rangedGrid(8, (nE + 1023) / 1024);

  k_prep<<<prepBlocks, 256, 0, stream>>>(coeff, bases, selfr, relw1, relw2,
                                         rfb, r1b, r2, W1, W2, WT1, WT2,
                                         ent, ent_ids, entbf, cursor, statsAll,
                                         ei, et, yk, keyA, payA, nE,
                                         nPairs, nKeys, cvtB, cntB, zeroB);

  // CSR: ONE kernel — fixed-capacity bucket fill (cursor doubles as counts)
  k_fillR<<<rangedGrid, 256, 0, stream>>>(keyA, payA, cursor, bucket, nE, rsz);

  // ---- layer 1 (fused agg+GEMM+stats) ----
  k_fused<<<fusedBlocks, 256, 0, stream>>>(entbf, rfb, cursor, bucket, WT1,
                                           Cb, rep1, M);
  k_norm<<<normBlocks, 256, 0, stream>>>((const uint4*)Cb, rep1, g1, b1,
                                         1.0f / M, (uint4*)xb, nQuad);

  // ---- layer 2 ----
  k_fused<<<fusedBlocks, 256, 0, stream>>>(xb, r1b, cursor, bucket, WT2,
                                           Cb, rep2, M);

  // ---- scoring (layer-2 norm fused in) ----
  k_score<<<(nT * 64 + 255) / 256, 256, 0, stream>>>((const unsigned int*)Cb, rep2,
                                                     g2, b2, 1.0f / M, r2,
                                                     triples, out, nT);
}

// Round 14
// 374.574 us; speedup vs baseline: 1.1807x; 1.1807x over previous
//
#include <hip/hip_runtime.h>
#include <cstdint>

typedef __attribute__((ext_vector_type(8))) short short8;
typedef __attribute__((ext_vector_type(4))) float f32x4;

static __device__ __forceinline__ unsigned short f2bf(float f) {
  unsigned int u = __float_as_uint(f);
  unsigned int r = (u + 0x7FFFu + ((u >> 16) & 1u)) >> 16;   // RNE
  return (unsigned short)r;
}
static __device__ __forceinline__ unsigned int pack2bf(float a, float b) {
  return (unsigned int)f2bf(a) | ((unsigned int)f2bf(b) << 16);
}
static __device__ __forceinline__ float2 bf2f(unsigned int u) {
  return make_float2(__uint_as_float(u << 16), __uint_as_float(u & 0xFFFF0000u));
}
static __device__ __forceinline__ void acc8(float* a, uint4 h, uint4 r) {
  float2 f, g;
  f = bf2f(h.x); g = bf2f(r.x); a[0] += f.x - g.x; a[1] += f.y - g.y;
  f = bf2f(h.y); g = bf2f(r.y); a[2] += f.x - g.x; a[3] += f.y - g.y;
  f = bf2f(h.z); g = bf2f(r.z); a[4] += f.x - g.x; a[5] += f.y - g.y;
  f = bf2f(h.w); g = bf2f(r.w); a[6] += f.x - g.x; a[7] += f.y - g.y;
}

// ---- one-shot prep kernel.  R14: histogram fused into the key/pay pass
// (atomicAdd piggybacks on the pass that already reads every edge; cross-XCD
// atomic latency hides under prep's streaming segments).  counts/stats
// zeroing moved to hipMemsetAsync before this kernel.
__global__ __launch_bounds__(256) void k_prep(
    const float* __restrict__ coeff, const float* __restrict__ bases,
    const float* __restrict__ selfr, const float* __restrict__ relw1,
    const float* __restrict__ relw2,
    unsigned int* __restrict__ rfb, unsigned int* __restrict__ r1b,
    float* __restrict__ r2,
    const float* __restrict__ W1, const float* __restrict__ W2,
    unsigned short* __restrict__ WT1, unsigned short* __restrict__ WT2,
    const float* __restrict__ ent, const int* __restrict__ ent_ids,
    unsigned int* __restrict__ entbf,
    int* __restrict__ counts,
    const int* __restrict__ ei, const int* __restrict__ et,
    const int* __restrict__ yk, int* __restrict__ keyA,
    unsigned int* __restrict__ payA, int nE,
    int nPairs, int cvtB) {
  int b = blockIdx.x, tid = threadIdx.x;
  if (b < 201) {
    __shared__ float row[2][128], r1row[2][128];
    int half = tid >> 7, c = tid & 127;
    int r = 2 * b + half;
    bool ok = (r <= 400);
    if (ok) {
      float v;
      if (r == 400) {
        v = selfr[c];
      } else {
        int rr = (r < 200) ? r : r - 200;
        float s = 0.f;
#pragma unroll 10
        for (int k = 0; k < 50; ++k) s += coeff[rr * 50 + k] * bases[k * 128 + c];
        v = (r < 200) ? s : -s;
      }
      row[half][c] = v;
    }
    __syncthreads();
    if (ok && c < 64) rfb[r * 64 + c] = pack2bf(row[half][2 * c], row[half][2 * c + 1]);
    if (ok) {
      float s = 0.f;
#pragma unroll 8
      for (int k = 0; k < 128; ++k) s += row[half][k] * relw1[k * 128 + c];
      r1row[half][c] = s;
    }
    __syncthreads();
    if (ok && c < 64) r1b[r * 64 + c] = pack2bf(r1row[half][2 * c], r1row[half][2 * c + 1]);
    if (ok) {
      float s = 0.f;
#pragma unroll 8
      for (int k = 0; k < 128; ++k) s += r1row[half][k] * relw2[k * 128 + c];
      r2[r * 128 + c] = s;
    }
  } else if (b < 585) {
    int idx = (b - 201) * 256 + tid;
    const int half = 128 * 384;
    const float* W = (idx < half) ? W1 : W2;
    unsigned short* WT = (idx < half) ? WT1 : WT2;
    int id2 = (idx < half) ? idx : idx - half;
    int n = id2 & 127, k = id2 >> 7;
    int kk = k >> 7, kr = k & 127;
    WT[(size_t)n * 384 + k] = f2bf(W[(size_t)kk * 16384 + kr * 128 + n]);
  } else if (b < 585 + cvtB) {
    int i = (b - 585) * 256 + tid;
    if (i < nPairs) {
      int e = i >> 6;
      int src = ent_ids[e];
      float2 v = *(const float2*)&ent[(size_t)src * 128 + (i & 63) * 2];
      entbf[i] = pack2bf(v.x, v.y);
    }
  } else {
    // key/pay precompute + fused histogram: one pass over edges
    int e = (b - (585 + cvtB)) * 1024 + tid;
#pragma unroll
    for (int i = 0; i < 4; ++i, e += 256) {
      if (e < nE) {
        int key = ei[nE + e] * 3 + yk[e];
        keyA[e] = key;
        payA[e] = (unsigned int)ei[e] | ((unsigned int)et[e] << 20);
        atomicAdd(&counts[key], 1);
      }
    }
  }
}

__global__ void k_scan1(const int* __restrict__ counts, int* __restrict__ local,
                        int* __restrict__ blockSums, int n) {
  __shared__ int sdata[1024];
  int tid = threadIdx.x;
  int i = blockIdx.x * 1024 + tid;
  int v = (i < n) ? counts[i] : 0;
  sdata[tid] = v;
  __syncthreads();
  for (int off = 1; off < 1024; off <<= 1) {
    int t = (tid >= off) ? sdata[tid - off] : 0;
    __syncthreads();
    sdata[tid] += t;
    __syncthreads();
  }
  if (i < n) local[i] = sdata[tid] - v;
  if (tid == 1023) blockSums[blockIdx.x] = sdata[1023];
}

__global__ void k_scan2(const int* __restrict__ blockSums, int* __restrict__ carries,
                        int* __restrict__ offsets, int n, int nb) {
  __shared__ int sdata[1024];
  int tid = threadIdx.x;
  int v = (tid < nb) ? blockSums[tid] : 0;
  sdata[tid] = v;
  __syncthreads();
  for (int off = 1; off < 1024; off <<= 1) {
    int t = (tid >= off) ? sdata[tid - off] : 0;
    __syncthreads();
    sdata[tid] += t;
    __syncthreads();
  }
  if (tid < nb) carries[tid] = sdata[tid] - v;
  if (tid == 1023) offsets[n] = sdata[1023];
}

__global__ void k_scan3(const int* __restrict__ local, const int* __restrict__ carries,
                        int* __restrict__ offsets, int* __restrict__ cursor, int n) {
  int i = blockIdx.x * 1024 + threadIdx.x;
  if (i >= n) return;
  int v = local[i] + carries[blockIdx.x];
  offsets[i] = v;
  cursor[i] = v;
}

// ---- CSR fill: range-partitioned (R9/R11-verified), key/pay inputs ----
__global__ __launch_bounds__(256) void k_fillR(const int* __restrict__ keyA,
                                               const unsigned int* __restrict__ payA,
                                               int* __restrict__ cursor,
                                               unsigned int* __restrict__ bucket, int nE, int rsz) {
  int r = blockIdx.x;
  int e0 = blockIdx.y * 1024;
#pragma unroll
  for (int i = 0; i < 4; ++i) {
    int e = e0 + i * 256 + threadIdx.x;
    if (e < nE) {
      int key = keyA[e];
      if (key / rsz == r) {
        int slot = atomicAdd(&cursor[key], 1);
        bucket[slot] = payA[e];
      }
    }
  }
}

// ---- FUSED gather-aggregate + GEMM + BN-stats, BM=32 (R10/R11/R12-verified) ----
__global__ __launch_bounds__(256, 6) void k_fused(
    const unsigned int* __restrict__ xb, const unsigned int* __restrict__ rb,
    const int* __restrict__ offsets, const unsigned int* __restrict__ packed,
    const unsigned short* __restrict__ WT, unsigned short* __restrict__ C,
    float* __restrict__ statsRep, int M) {
  __shared__ unsigned short As[32][392];
  const int tid = threadIdx.x;
  const int m0 = blockIdx.x * 32;
  const int wave = tid >> 6, lane = tid & 63;
  const int quad = lane >> 4, l16 = lane & 15;
  const int qid = (wave << 2) | quad;          // 0..15: rows 2qid, 2qid+1

  // ---- gather phase: contiguous edge walk over 6 segments ----
  {
    const int dst0 = m0 + 2 * qid;
    int b0, b1, b2, b3, b4, b5, b6;
    if (dst0 + 1 < M) {
      const int base = dst0 * 3;
      b0 = offsets[base];     b1 = offsets[base + 1];
      b2 = offsets[base + 2]; b3 = offsets[base + 3];
      b4 = offsets[base + 4]; b5 = offsets[base + 5];
      b6 = offsets[base + 6];
    } else if (dst0 < M) {
      const int base = dst0 * 3;
      b0 = offsets[base];     b1 = offsets[base + 1];
      b2 = offsets[base + 2]; b3 = offsets[base + 3];
      b4 = b3; b5 = b3; b6 = b3;
    } else {
      b0 = b1 = b2 = b3 = b4 = b5 = b6 = 0;
    }
    float ac[8] = {};
    int seg = 0;
    int nextB = b1;
    int j = b0;
    const int hi = b6;
    unsigned short* lds0 = &As[2 * qid][0];

    auto flushSeg = [&]() {
      int rowOff = (seg >= 3) ? 392 : 0;
      int cls = seg - ((seg >= 3) ? 3 : 0);
      uint4 ov;
      ov.x = pack2bf(ac[0], ac[1]);
      ov.y = pack2bf(ac[2], ac[3]);
      ov.z = pack2bf(ac[4], ac[5]);
      ov.w = pack2bf(ac[6], ac[7]);
      *(uint4*)(lds0 + rowOff + cls * 128 + l16 * 8) = ov;
#pragma unroll
      for (int z = 0; z < 8; ++z) ac[z] = 0.f;
      ++seg;
      nextB = (seg == 1) ? b2 : (seg == 2) ? b3 : (seg == 3) ? b4
            : (seg == 4) ? b5 : b6;
    };

    if (j < hi) {
      int jc1 = (j + 1 < hi) ? j + 1 : j;
      unsigned int q0 = packed[j], q1 = packed[jc1];
      int s0 = q0 & 0xFFFFF, t0 = q0 >> 20;
      int s1 = q1 & 0xFFFFF, t1 = q1 >> 20;
      uint4 h0 = *(const uint4*)&xb[(size_t)s0 * 64 + l16 * 4];
      uint4 r0 = *(const uint4*)&rb[(size_t)t0 * 64 + l16 * 4];
      uint4 h1 = *(const uint4*)&xb[(size_t)s1 * 64 + l16 * 4];
      uint4 r1 = *(const uint4*)&rb[(size_t)t1 * 64 + l16 * 4];
      while (j < hi) {
        int jp2 = (j + 2 < hi) ? j + 2 : hi - 1;
        int jp3 = (j + 3 < hi) ? j + 3 : hi - 1;
        unsigned int q2 = packed[jp2], q3 = packed[jp3];
        int s2 = q2 & 0xFFFFF, t2 = q2 >> 20;
        int s3 = q3 & 0xFFFFF, t3 = q3 >> 20;
        uint4 th0 = *(const uint4*)&xb[(size_t)s2 * 64 + l16 * 4];
        uint4 tr0 = *(const uint4*)&rb[(size_t)t2 * 64 + l16 * 4];
        uint4 th1 = *(const uint4*)&xb[(size_t)s3 * 64 + l16 * 4];
        uint4 tr1 = *(const uint4*)&rb[(size_t)t3 * 64 + l16 * 4];
        while (j == nextB) flushSeg();
        acc8(ac, h0, r0);
        ++j;
        if (j < hi) {
          while (j == nextB) flushSeg();
          acc8(ac, h1, r1);
          ++j;
        }
        h0 = th0; r0 = tr0; h1 = th1; r1 = tr1;
      }
    }
    while (seg < 6) flushSeg();
  }
  __syncthreads();

  // ---- GEMM phase: C[32x128] = As[32x384] @ WT^T, B streamed from L2 ----
  const unsigned short* Wp = WT + (size_t)(wave * 32 + l16) * 384 + quad * 8;
  short8 bc0 = *(const short8*)(Wp);
  short8 bc1 = *(const short8*)(Wp + 16 * 384);
  f32x4 acc[2][2] = {};
#pragma unroll 1
  for (int it = 0; it < 12; ++it) {
    short8 bn0, bn1;
    if (it < 11) {
      bn0 = *(const short8*)(Wp + (it + 1) * 32);
      bn1 = *(const short8*)(Wp + 16 * 384 + (it + 1) * 32);
    }
    short8 a0 = *(const short8*)&As[l16][it * 32 + quad * 8];
    short8 a1 = *(const short8*)&As[16 + l16][it * 32 + quad * 8];
    acc[0][0] = __builtin_amdgcn_mfma_f32_16x16x32_bf16(a0, bc0, acc[0][0], 0, 0, 0);
    acc[0][1] = __builtin_amdgcn_mfma_f32_16x16x32_bf16(a0, bc1, acc[0][1], 0, 0, 0);
    acc[1][0] = __builtin_amdgcn_mfma_f32_16x16x32_bf16(a1, bc0, acc[1][0], 0, 0, 0);
    acc[1][1] = __builtin_amdgcn_mfma_f32_16x16x32_bf16(a1, bc1, acc[1][1], 0, 0, 0);
    if (it < 11) { bc0 = bn0; bc1 = bn1; }
  }

  // ---- epilogue: bf16 C store + BN stats (in-register quad reduce) ----
  float ps[2] = {}, pq[2] = {};
#pragma unroll
  for (int t = 0; t < 2; ++t)
#pragma unroll
    for (int reg = 0; reg < 4; ++reg) {
      int m = m0 + t * 16 + quad * 4 + reg;
      if (m < M) {
#pragma unroll
        for (int ct = 0; ct < 2; ++ct) {
          float v = acc[t][ct][reg];
          int col = wave * 32 + ct * 16 + l16;
          C[(size_t)m * 128 + col] = f2bf(v);
          ps[ct] += v; pq[ct] += v * v;
        }
      }
    }
#pragma unroll
  for (int ct = 0; ct < 2; ++ct) {
    ps[ct] += __shfl_xor(ps[ct], 16);
    ps[ct] += __shfl_xor(ps[ct], 32);
    pq[ct] += __shfl_xor(pq[ct], 16);
    pq[ct] += __shfl_xor(pq[ct], 32);
  }
  if (quad == 0) {
    float* rep = statsRep + ((blockIdx.x & 31) << 8);
#pragma unroll
    for (int ct = 0; ct < 2; ++ct) {
      int col = wave * 32 + ct * 16 + l16;
      atomicAdd(&rep[col], ps[ct]);
      atomicAdd(&rep[128 + col], pq[ct]);
    }
  }
}

// norm + tanh (layer 1 only), uint4-vectorized; inline replica collapse
__global__ void k_norm(const uint4* __restrict__ Cb4, const float* __restrict__ rep,
                       const float* __restrict__ gamma, const float* __restrict__ beta,
                       float invN, uint4* __restrict__ xb4, int nQuad) {
  __shared__ float sc_s[128], bi_s[128];
  if (threadIdx.x < 128) {
    int c = threadIdx.x;
    float s = 0.f, q = 0.f;
#pragma unroll
    for (int r = 0; r < 32; ++r) {
      s += rep[r * 256 + c];
      q += rep[r * 256 + 128 + c];
    }
    float mean = s * invN;
    float var = fmaxf(q * invN - mean * mean, 0.f);
    float sc = rsqrtf(var + 1e-5f) * gamma[c];
    sc_s[c] = sc;
    bi_s[c] = beta[c] - mean * sc;
  }
  __syncthreads();
  int i = blockIdx.x * blockDim.x + threadIdx.x;
  if (i >= nQuad) return;
  uint4 v = Cb4[i];
  int j = (i * 4) & 63;
  uint4 o;
  float2 f;
  f = bf2f(v.x);
  o.x = pack2bf(tanhf(fmaf(f.x, sc_s[2*j],   bi_s[2*j])),   tanhf(fmaf(f.y, sc_s[2*j+1], bi_s[2*j+1])));
  f = bf2f(v.y);
  o.y = pack2bf(tanhf(fmaf(f.x, sc_s[2*j+2], bi_s[2*j+2])), tanhf(fmaf(f.y, sc_s[2*j+3], bi_s[2*j+3])));
  f = bf2f(v.z);
  o.z = pack2bf(tanhf(fmaf(f.x, sc_s[2*j+4], bi_s[2*j+4])), tanhf(fmaf(f.y, sc_s[2*j+5], bi_s[2*j+5])));
  f = bf2f(v.w);
  o.w = pack2bf(tanhf(fmaf(f.x, sc_s[2*j+6], bi_s[2*j+6])), tanhf(fmaf(f.y, sc_s[2*j+7], bi_s[2*j+7])));
  xb4[i] = o;
}

// scoring with layer-2 norm fused (R12-verified)
__global__ void k_score(const unsigned int* __restrict__ Cbu, const float* __restrict__ rep,
                        const float* __restrict__ gamma, const float* __restrict__ beta,
                        float invN, const float* __restrict__ r,
                        const int* __restrict__ triples, float* __restrict__ out, int nT) {
  __shared__ float sc_s[128], bi_s[128];
  if (threadIdx.x < 128) {
    int c = threadIdx.x;
    float s = 0.f, q = 0.f;
#pragma unroll
    for (int rr = 0; rr < 32; ++rr) {
      s += rep[rr * 256 + c];
      q += rep[rr * 256 + 128 + c];
    }
    float mean = s * invN;
    float var = fmaxf(q * invN - mean * mean, 0.f);
    float sc = rsqrtf(var + 1e-5f) * gamma[c];
    sc_s[c] = sc;
    bi_s[c] = beta[c] - mean * sc;
  }
  __syncthreads();
  int gid = blockIdx.x * blockDim.x + threadIdx.x;
  int t = gid >> 6;
  if (t >= nT) return;
  int lane = gid & 63;
  int h = triples[t * 3], rel = triples[t * 3 + 1], tl = triples[t * 3 + 2];
  float2 a = bf2f(Cbu[(size_t)h * 64 + lane]);
  float2 b = *(const float2*)&r[(size_t)rel * 128 + lane * 2];
  float2 cc = bf2f(Cbu[(size_t)tl * 64 + lane]);
  float ax = tanhf(fmaf(a.x, sc_s[2 * lane], bi_s[2 * lane]));
  float ay = tanhf(fmaf(a.y, sc_s[2 * lane + 1], bi_s[2 * lane + 1]));
  float cx = tanhf(fmaf(cc.x, sc_s[2 * lane], bi_s[2 * lane]));
  float cy = tanhf(fmaf(cc.y, sc_s[2 * lane + 1], bi_s[2 * lane + 1]));
  float s = fabsf(ax + b.x - cx) + fabsf(ay + b.y - cy);
#pragma unroll
  for (int off = 32; off > 0; off >>= 1) s += __shfl_down(s, off);
  if (lane == 0) out[t] = s;
}

extern "C" void kernel_launch(void* const* d_in, const int* in_sizes, int n_in,
                              void* d_out, int out_size, void* d_ws, size_t ws_size,
                              hipStream_t stream) {
  const float* ent   = (const float*)d_in[0];
  const float* bases = (const float*)d_in[1];
  const float* coeff = (const float*)d_in[2];
  const float* selfr = (const float*)d_in[3];
  const float* W1    = (const float*)d_in[4];
  const float* relw1 = (const float*)d_in[5];
  const float* g1    = (const float*)d_in[6];
  const float* b1    = (const float*)d_in[7];
  const float* W2    = (const float*)d_in[8];
  const float* relw2 = (const float*)d_in[9];
  const float* g2    = (const float*)d_in[10];
  const float* b2    = (const float*)d_in[11];
  const int* ent_ids = (const int*)d_in[12];
  const int* ei      = (const int*)d_in[13];
  const int* et      = (const int*)d_in[14];
  const int* yk      = (const int*)d_in[15];
  const int* triples = (const int*)d_in[16];

  const int M  = in_sizes[0] / 128;   // 100000
  const int nE = in_sizes[14];        // 800000
  const int nT = in_sizes[16] / 3;    // 4096
  const int nKeys = M * 3;
  const int nScanBlocks = (nKeys + 1023) / 1024;
  const int rsz = (nKeys + 7) / 8;

  // workspace layout (~95 MB)
  float* p = (float*)d_ws;
  float* r2    = p; p += 401 * 128;
  float* statsAll = p; p += 16896;     // rep1(32x256) | rep2(32x256) | spare
  float* rep1 = statsAll;
  float* rep2 = statsAll + 32 * 256;
  unsigned short* Cb  = (unsigned short*)p;                       // M*128 bf16
  unsigned int* entbf = (unsigned int*)(Cb + (size_t)M * 128);    // M*64
  unsigned int* xb    = entbf + (size_t)M * 64;                   // M*64
  unsigned int* rfb   = xb + (size_t)M * 64;                      // 401*64
  unsigned int* r1b   = rfb + 401 * 64;                           // 401*64
  unsigned short* WT1 = (unsigned short*)(r1b + 401 * 64);
  unsigned short* WT2 = WT1 + 128 * 384;
  int* counts  = (int*)(WT2 + 128 * 384);
  int* offsets = counts + nKeys;
  int* cursor  = offsets + nKeys + 1;
  int* slocal  = cursor + nKeys;
  int* sblock  = slocal + nKeys;
  int* scarry  = sblock + nScanBlocks;
  unsigned int* bucket = (unsigned int*)(scarry + nScanBlocks);   // nE
  int* keyA = (int*)(bucket + nE);                                // nE
  unsigned int* payA = (unsigned int*)(keyA + nE);                // nE

  float* out = (float*)d_out;

  const int nPairs = M * 64;
  const int nQuad  = M * 16;
  const int cvtB = (nPairs + 255) / 256;
  const int kpB = (nE + 1023) / 1024;
  const int prepBlocks = 585 + cvtB + kpB;
  const int fusedBlocks = (M + 31) / 32;
  const int normBlocks = (nQuad + 255) / 256;
  const dim3 rangedGrid(8, (nE + 1023) / 1024);

  // zero counts + stat replicas (stream-ordered before prep's fused histogram)
  hipMemsetAsync(counts, 0, (size_t)nKeys * sizeof(int), stream);
  hipMemsetAsync(statsAll, 0, (size_t)16896 * sizeof(float), stream);

  k_prep<<<prepBlocks, 256, 0, stream>>>(coeff, bases, selfr, relw1, relw2,
                                         rfb, r1b, r2, W1, W2, WT1, WT2,
                                         ent, ent_ids, entbf, counts,
                                         ei, et, yk, keyA, payA, nE,
                                         nPairs, cvtB);

  // CSR over (dst, class): scan the fused histogram, ranged fill
  k_scan1<<<nScanBlocks, 1024, 0, stream>>>(counts, slocal, sblock, nKeys);
  k_scan2<<<1, 1024, 0, stream>>>(sblock, scarry, offsets, nKeys, nScanBlocks);
  k_scan3<<<nScanBlocks, 1024, 0, stream>>>(slocal, scarry, offsets, cursor, nKeys);
  k_fillR<<<rangedGrid, 256, 0, stream>>>(keyA, payA, cursor, bucket, nE, rsz);

  // ---- layer 1 (fused agg+GEMM+stats) ----
  k_fused<<<fusedBlocks, 256, 0, stream>>>(entbf, rfb, offsets, bucket, WT1,
                                           Cb, rep1, M);
  k_norm<<<normBlocks, 256, 0, stream>>>((const uint4*)Cb, rep1, g1, b1,
                                         1.0f / M, (uint4*)xb, nQuad);

  // ---- layer 2 ----
  k_fused<<<fusedBlocks, 256, 0, stream>>>(xb, r1b, offsets, bucket, WT2,
                                           Cb, rep2, M);

  // ---- scoring (layer-2 norm fused in) ----
  k_score<<<(nT * 64 + 255) / 256, 256, 0, stream>>>((const unsigned int*)Cb, rep2,
                                                     g2, b2, 1.0f / M, r2,
                                                     triples, out, nT);
}